// Round 1
// baseline (417.928 us; speedup 1.0000x reference)
//
#include <hip/hip_runtime.h>

#define BB 16
#define SS 2048
#define EE 4
#define FFD 16
#define NTOK 17
#define MAXREL 32
#define NREL 63   // 2*MAXREL-1
#define LOG2E 1.4426950408889634f

// x layout: (B, S, 4) float, as float4 per row.

__global__ __launch_bounds__(256) void embed_kernel(
    const int* __restrict__ patches, const int* __restrict__ mask,
    const float* __restrict__ em, float4* __restrict__ x0)
{
    int i = blockIdx.x * 256 + threadIdx.x;  // 0..B*S-1
    int p = patches[i];
    int m = mask[i];
    int row = m ? 16 : p;
    const float* r = em + row * 4;
    x0[i] = make_float4(r[0], r[1], r[2], r[3]);
}

__global__ __launch_bounds__(256) void layer_kernel(
    const float4* __restrict__ x_in, float4* __restrict__ x_out,
    const int* __restrict__ mask,
    const float* __restrict__ rel_emb,   // (63,4) this layer
    const float* __restrict__ w1, const float* __restrict__ b1,
    const float* __restrict__ w2, const float* __restrict__ b2,
    const float* __restrict__ ln1w, const float* __restrict__ ln1b,
    const float* __restrict__ ln2w, const float* __restrict__ ln2b)
{
    __shared__ float4 kv[SS];            // 32 KB: full x_b (keys == queries)
    __shared__ unsigned char mk[SS];     // 2 KB
    __shared__ float bias2[64];          // rel bias pre-scaled by log2e
    __shared__ float w1s[64], b1s[16], w2s[64], b2s[4];
    __shared__ float ln1ws[4], ln1bs[4], ln2ws[4], ln2bs[4];
    __shared__ float mrg[4][128][7];     // per-wave partials: m,l,acc0..3 (stride 7: 2-way banks)

    const int b = blockIdx.y;
    const int chunk = blockIdx.x;        // 0..15, 128 query rows each
    const int tid = threadIdx.x;

    // ---- stage ----
    const float4* xb = x_in + b * SS;
    #pragma unroll
    for (int k = 0; k < 8; ++k) kv[tid + 256*k] = xb[tid + 256*k];
    const int* mb = mask + b * SS;
    #pragma unroll
    for (int k = 0; k < 8; ++k) mk[tid + 256*k] = (unsigned char)mb[tid + 256*k];
    if (tid < NREL) {
        const float* re = rel_emb + tid * 4;
        bias2[tid] = (re[0] + re[1] + re[2] + re[3]) * LOG2E;
    }
    if (tid < 64) { w1s[tid] = w1[tid]; w2s[tid] = w2[tid]; }
    if (tid < 16) b1s[tid] = b1[tid];
    if (tid < 4) {
        b2s[tid] = b2[tid];
        ln1ws[tid] = ln1w[tid]; ln1bs[tid] = ln1b[tid];
        ln2ws[tid] = ln2w[tid]; ln2bs[tid] = ln2b[tid];
    }
    __syncthreads();

    const int wave = tid >> 6;
    const int lane = tid & 63;
    const int row0 = chunk * 128 + lane;  // this lane's 2 query rows
    const int row1 = row0 + 64;

    const float4 q0 = kv[row0];
    const float4 q1 = kv[row1];
    float m0 = -1e30f, l0 = 0.f, a00 = 0.f, a01 = 0.f, a02 = 0.f, a03 = 0.f;
    float m1 = -1e30f, l1 = 0.f, a10 = 0.f, a11 = 0.f, a12 = 0.f, a13 = 0.f;

    const int jbase = wave * 512;         // each wave owns 512 keys
    for (int jj = 0; jj < 512; ++jj) {
        const int j = jbase + jj;
        if (!mk[j]) continue;             // wave-uniform skip (~50% of keys)
        const float4 k4 = kv[j];
        const float dot_scale = 0.5f * LOG2E;   // (dot/sqrt(4)) * log2(e)
        // row 0
        {
            int d = row0 - j + (MAXREL - 1);
            d = d < 0 ? 0 : (d > NREL - 1 ? NREL - 1 : d);
            float s = (q0.x*k4.x + q0.y*k4.y + q0.z*k4.z + q0.w*k4.w) * dot_scale + bias2[d];
            if (s > m0) {
                float c = exp2f(m0 - s);
                l0 *= c; a00 *= c; a01 *= c; a02 *= c; a03 *= c;
                m0 = s;
            }
            float p = exp2f(s - m0);
            l0 += p;
            a00 += p * k4.x; a01 += p * k4.y; a02 += p * k4.z; a03 += p * k4.w;
        }
        // row 1
        {
            int d = row1 - j + (MAXREL - 1);
            d = d < 0 ? 0 : (d > NREL - 1 ? NREL - 1 : d);
            float s = (q1.x*k4.x + q1.y*k4.y + q1.z*k4.z + q1.w*k4.w) * dot_scale + bias2[d];
            if (s > m1) {
                float c = exp2f(m1 - s);
                l1 *= c; a10 *= c; a11 *= c; a12 *= c; a13 *= c;
                m1 = s;
            }
            float p = exp2f(s - m1);
            l1 += p;
            a10 += p * k4.x; a11 += p * k4.y; a12 += p * k4.z; a13 += p * k4.w;
        }
    }

    // ---- merge 4 wave-partials per row ----
    {
        float* g = mrg[wave][lane];
        g[0] = m0; g[1] = l0; g[2] = a00; g[3] = a01; g[4] = a02; g[5] = a03;
        float* h = mrg[wave][lane + 64];
        h[0] = m1; h[1] = l1; h[2] = a10; h[3] = a11; h[4] = a12; h[5] = a13;
    }
    __syncthreads();

    if (tid < 128) {
        const int r = tid;
        float M = -1e30f;
        #pragma unroll
        for (int w = 0; w < 4; ++w) M = fmaxf(M, mrg[w][r][0]);
        float L = 0.f, o0 = 0.f, o1 = 0.f, o2 = 0.f, o3 = 0.f;
        #pragma unroll
        for (int w = 0; w < 4; ++w) {
            float c = exp2f(mrg[w][r][0] - M);
            L  += c * mrg[w][r][1];
            o0 += c * mrg[w][r][2]; o1 += c * mrg[w][r][3];
            o2 += c * mrg[w][r][4]; o3 += c * mrg[w][r][5];
        }
        const float inv = 1.0f / L;
        const int i = chunk * 128 + r;
        const float4 x = kv[i];
        float h0 = x.x + o0 * inv, h1 = x.y + o1 * inv, h2 = x.z + o2 * inv, h3 = x.w + o3 * inv;
        // LN1
        float mu = 0.25f * (h0 + h1 + h2 + h3);
        float v0 = h0 - mu, v1 = h1 - mu, v2 = h2 - mu, v3 = h3 - mu;
        float var = 0.25f * (v0*v0 + v1*v1 + v2*v2 + v3*v3);
        float rstd = rsqrtf(var + 1e-5f);
        h0 = v0 * rstd * ln1ws[0] + ln1bs[0];
        h1 = v1 * rstd * ln1ws[1] + ln1bs[1];
        h2 = v2 * rstd * ln1ws[2] + ln1bs[2];
        h3 = v3 * rstd * ln1ws[3] + ln1bs[3];
        // FF: relu(h @ w1 + b1) @ w2 + b2, residual
        float f0 = b2s[0], f1 = b2s[1], f2 = b2s[2], f3 = b2s[3];
        #pragma unroll
        for (int k = 0; k < FFD; ++k) {
            float f = h0*w1s[k] + h1*w1s[16 + k] + h2*w1s[32 + k] + h3*w1s[48 + k] + b1s[k];
            f = fmaxf(f, 0.f);
            f0 += f * w2s[k*4 + 0]; f1 += f * w2s[k*4 + 1];
            f2 += f * w2s[k*4 + 2]; f3 += f * w2s[k*4 + 3];
        }
        float t0 = h0 + f0, t1 = h1 + f1, t2 = h2 + f2, t3 = h3 + f3;
        // LN2
        mu = 0.25f * (t0 + t1 + t2 + t3);
        v0 = t0 - mu; v1 = t1 - mu; v2 = t2 - mu; v3 = t3 - mu;
        var = 0.25f * (v0*v0 + v1*v1 + v2*v2 + v3*v3);
        rstd = rsqrtf(var + 1e-5f);
        x_out[b * SS + i] = make_float4(
            v0 * rstd * ln2ws[0] + ln2bs[0],
            v1 * rstd * ln2ws[1] + ln2bs[1],
            v2 * rstd * ln2ws[2] + ln2bs[2],
            v3 * rstd * ln2ws[3] + ln2bs[3]);
    }
}

__global__ __launch_bounds__(256) void fc_kernel(
    const float4* __restrict__ x, const float* __restrict__ fw,
    const float* __restrict__ fb, float* __restrict__ out)
{
    __shared__ float w[NTOK * 4];
    __shared__ float bbias[NTOK];
    const int tid = threadIdx.x;
    if (tid < NTOK * 4) w[tid] = fw[tid];
    if (tid < NTOK) bbias[tid] = fb[tid];
    __syncthreads();
    const int i = blockIdx.x * 256 + tid;
    const float4 v = x[i];
    float* o = out + (size_t)i * NTOK;
    #pragma unroll
    for (int t = 0; t < NTOK; ++t)
        o[t] = v.x * w[t*4] + v.y * w[t*4 + 1] + v.z * w[t*4 + 2] + v.w * w[t*4 + 3] + bbias[t];
}

extern "C" void kernel_launch(void* const* d_in, const int* in_sizes, int n_in,
                              void* d_out, int out_size, void* d_ws, size_t ws_size,
                              hipStream_t stream) {
    const int*   patches = (const int*)d_in[0];
    const int*   mask    = (const int*)d_in[1];
    const float* em      = (const float*)d_in[2];
    const float* rel     = (const float*)d_in[3];
    const float* w1      = (const float*)d_in[4];
    const float* b1      = (const float*)d_in[5];
    const float* w2      = (const float*)d_in[6];
    const float* b2      = (const float*)d_in[7];
    const float* ln1w    = (const float*)d_in[8];
    const float* ln1b    = (const float*)d_in[9];
    const float* ln2w    = (const float*)d_in[10];
    const float* ln2b    = (const float*)d_in[11];
    const float* fcw     = (const float*)d_in[12];
    const float* fcb     = (const float*)d_in[13];
    float* out = (float*)d_out;

    float4* xA = (float4*)d_ws;
    float4* xB = xA + BB * SS;

    embed_kernel<<<BB * SS / 256, 256, 0, stream>>>(patches, mask, em, xA);

    float4* xi = xA;
    float4* xo = xB;
    for (int l = 0; l < 4; ++l) {
        layer_kernel<<<dim3(16, BB), 256, 0, stream>>>(
            xi, xo, mask,
            rel + l * NREL * 4,
            w1 + l * 64, b1 + l * 16, w2 + l * 64, b2 + l * 4,
            ln1w + l * 4, ln1b + l * 4, ln2w + l * 4, ln2b + l * 4);
        float4* t = xi; xi = xo; xo = t;
    }

    fc_kernel<<<BB * SS / 256, 256, 0, stream>>>(xi, fcw, fcb, out);
}

// Round 2
// 176.943 us; speedup vs baseline: 2.3619x; 2.3619x over previous
//
#include <hip/hip_runtime.h>

#define BB 16
#define SS 2048
#define EE 4
#define FFD 16
#define NTOK 17
#define MAXREL 32
#define NREL 63   // 2*MAXREL-1
#define LOG2E 1.4426950408889634f
#define SHIFT 10.0f   // fixed softmax shift (exp2 domain); scores bounded well within fp32

// x layout: (B, S, 4) float, as float4 per row.

__global__ __launch_bounds__(256) void embed_kernel(
    const int* __restrict__ patches, const int* __restrict__ mask,
    const float* __restrict__ em, float4* __restrict__ x0)
{
    int i = blockIdx.x * 256 + threadIdx.x;  // 0..B*S-1
    int p = patches[i];
    int m = mask[i];
    int row = m ? 16 : p;
    const float* r = em + row * 4;
    x0[i] = make_float4(r[0], r[1], r[2], r[3]);
}

// Block: 1024 threads = 16 waves. Grid: (16 chunks) x (16 batches).
// Each block: one batch, 128 query rows (2 rows/lane). Each wave owns 128 keys.
// Fixed-shift softmax (no online max): partials are plain sums -> merge is a sum.
__global__ __launch_bounds__(1024, 4) void layer_kernel(
    const float4* __restrict__ x_in, float4* __restrict__ x_out,
    const int* __restrict__ mask,
    const float* __restrict__ rel_emb,   // (63,4) this layer
    const float* __restrict__ w1, const float* __restrict__ b1,
    const float* __restrict__ w2, const float* __restrict__ b2,
    const float* __restrict__ ln1w, const float* __restrict__ ln1b,
    const float* __restrict__ ln2w, const float* __restrict__ ln2b)
{
    __shared__ float4 kv[SS];                      // 32 KB
    __shared__ unsigned long long mbits[32];       // mask bitmask, 64 keys/word
    __shared__ float bias2[64];                    // rel bias * log2e - SHIFT
    __shared__ float4 accs[16][128];               // 32 KB per-wave partial sums
    __shared__ float ls[16][128];                  // 8 KB per-wave partial l
    __shared__ float w1s[64], b1s[16], w2s[64], b2s[4];
    __shared__ float ln1ws[4], ln1bs[4], ln2ws[4], ln2bs[4];

    const int b = blockIdx.y;
    const int chunk = blockIdx.x;        // 0..15, 128 query rows each
    const int tid = threadIdx.x;
    const int wave = tid >> 6;
    const int lane = tid & 63;

    // ---- stage ----
    const float4* xb = x_in + b * SS;
    kv[tid] = xb[tid];
    kv[tid + 1024] = xb[tid + 1024];
    const int* mb = mask + b * SS;
    {
        unsigned long long bt = __ballot(mb[tid] != 0);
        if (lane == 0) mbits[wave] = bt;
        unsigned long long bt2 = __ballot(mb[tid + 1024] != 0);
        if (lane == 0) mbits[16 + wave] = bt2;
    }
    if (tid < NREL) {
        const float* re = rel_emb + tid * 4;
        bias2[tid] = (re[0] + re[1] + re[2] + re[3]) * LOG2E - SHIFT;
    }
    if (tid == NREL) bias2[63] = 0.f;
    if (tid >= 128 && tid < 192) { int k = tid - 128; w1s[k] = w1[k]; w2s[k] = w2[k]; }
    if (tid >= 192 && tid < 208) b1s[tid - 192] = b1[tid - 192];
    if (tid >= 208 && tid < 212) b2s[tid - 208] = b2[tid - 208];
    if (tid >= 212 && tid < 216) { ln1ws[tid-212] = ln1w[tid-212]; ln1bs[tid-212] = ln1b[tid-212]; }
    if (tid >= 216 && tid < 220) { ln2ws[tid-216] = ln2w[tid-216]; ln2bs[tid-216] = ln2b[tid-216]; }
    __syncthreads();

    const int row0 = chunk * 128 + lane;  // this lane's 2 query rows
    const int row1 = row0 + 64;

    const float4 q0 = kv[row0];
    const float4 q1 = kv[row1];
    const float sc = 0.5f * LOG2E;        // 1/sqrt(E) * log2(e)
    const float q0x = q0.x * sc, q0y = q0.y * sc, q0z = q0.z * sc, q0w = q0.w * sc;
    const float q1x = q1.x * sc, q1y = q1.y * sc, q1z = q1.z * sc, q1w = q1.w * sc;

    float l0 = 0.f, a00 = 0.f, a01 = 0.f, a02 = 0.f, a03 = 0.f;
    float l1 = 0.f, a10 = 0.f, a11 = 0.f, a12 = 0.f, a13 = 0.f;

    #pragma unroll
    for (int g = 0; g < 2; ++g) {
        const int grp = wave * 2 + g;
        const int kbase = grp * 64;
        unsigned long long bits = mbits[grp];
        // force into SGPRs: scalar bit-scan loop (s_ff1 / s_and), branch-free vector body
        unsigned lo = __builtin_amdgcn_readfirstlane((unsigned)bits);
        unsigned hi = __builtin_amdgcn_readfirstlane((unsigned)(bits >> 32));
        unsigned long long sb = ((unsigned long long)hi << 32) | lo;
        while (sb) {
            const int t = __builtin_ctzll(sb);
            sb &= sb - 1;
            const int j = kbase + t;
            const float4 k4 = kv[j];
            const int du = row0 - j + (MAXREL - 1);
            const int d0 = min(max(du, 0), NREL - 1);
            const int d1 = min(max(du + 64, 0), NREL - 1);
            float s0 = fmaf(q0x, k4.x, fmaf(q0y, k4.y, fmaf(q0z, k4.z, fmaf(q0w, k4.w, bias2[d0]))));
            float s1 = fmaf(q1x, k4.x, fmaf(q1y, k4.y, fmaf(q1z, k4.z, fmaf(q1w, k4.w, bias2[d1]))));
            float p0 = exp2f(s0);
            float p1 = exp2f(s1);
            l0 += p0; l1 += p1;
            a00 = fmaf(p0, k4.x, a00); a01 = fmaf(p0, k4.y, a01);
            a02 = fmaf(p0, k4.z, a02); a03 = fmaf(p0, k4.w, a03);
            a10 = fmaf(p1, k4.x, a10); a11 = fmaf(p1, k4.y, a11);
            a12 = fmaf(p1, k4.z, a12); a13 = fmaf(p1, k4.w, a13);
        }
    }

    accs[wave][lane]      = make_float4(a00, a01, a02, a03);
    ls[wave][lane]        = l0;
    accs[wave][lane + 64] = make_float4(a10, a11, a12, a13);
    ls[wave][lane + 64]   = l1;
    __syncthreads();

    // ---- merge (plain sums) + epilogue ----
    if (tid < 128) {
        const int r = tid;
        float4 o4 = accs[0][r];
        float L = ls[0][r];
        #pragma unroll
        for (int w = 1; w < 16; ++w) {
            float4 t4 = accs[w][r];
            o4.x += t4.x; o4.y += t4.y; o4.z += t4.z; o4.w += t4.w;
            L += ls[w][r];
        }
        const float inv = 1.0f / L;
        const int i = chunk * 128 + r;
        const float4 x = kv[i];
        float h0 = x.x + o4.x * inv, h1 = x.y + o4.y * inv;
        float h2 = x.z + o4.z * inv, h3 = x.w + o4.w * inv;
        // LN1
        float mu = 0.25f * (h0 + h1 + h2 + h3);
        float v0 = h0 - mu, v1 = h1 - mu, v2 = h2 - mu, v3 = h3 - mu;
        float var = 0.25f * (v0*v0 + v1*v1 + v2*v2 + v3*v3);
        float rstd = rsqrtf(var + 1e-5f);
        h0 = v0 * rstd * ln1ws[0] + ln1bs[0];
        h1 = v1 * rstd * ln1ws[1] + ln1bs[1];
        h2 = v2 * rstd * ln1ws[2] + ln1bs[2];
        h3 = v3 * rstd * ln1ws[3] + ln1bs[3];
        // FF: relu(h @ w1 + b1) @ w2 + b2, residual
        float f0 = b2s[0], f1 = b2s[1], f2 = b2s[2], f3 = b2s[3];
        #pragma unroll
        for (int k = 0; k < FFD; ++k) {
            float f = h0*w1s[k] + h1*w1s[16 + k] + h2*w1s[32 + k] + h3*w1s[48 + k] + b1s[k];
            f = fmaxf(f, 0.f);
            f0 += f * w2s[k*4 + 0]; f1 += f * w2s[k*4 + 1];
            f2 += f * w2s[k*4 + 2]; f3 += f * w2s[k*4 + 3];
        }
        float t0 = h0 + f0, t1 = h1 + f1, t2 = h2 + f2, t3 = h3 + f3;
        // LN2
        mu = 0.25f * (t0 + t1 + t2 + t3);
        v0 = t0 - mu; v1 = t1 - mu; v2 = t2 - mu; v3 = t3 - mu;
        var = 0.25f * (v0*v0 + v1*v1 + v2*v2 + v3*v3);
        rstd = rsqrtf(var + 1e-5f);
        x_out[b * SS + i] = make_float4(
            v0 * rstd * ln2ws[0] + ln2bs[0],
            v1 * rstd * ln2ws[1] + ln2bs[1],
            v2 * rstd * ln2ws[2] + ln2bs[2],
            v3 * rstd * ln2ws[3] + ln2bs[3]);
    }
}

__global__ __launch_bounds__(256) void fc_kernel(
    const float4* __restrict__ x, const float* __restrict__ fw,
    const float* __restrict__ fb, float* __restrict__ out)
{
    __shared__ float w[NTOK * 4];
    __shared__ float bbias[NTOK];
    const int tid = threadIdx.x;
    if (tid < NTOK * 4) w[tid] = fw[tid];
    if (tid < NTOK) bbias[tid] = fb[tid];
    __syncthreads();
    const int i = blockIdx.x * 256 + tid;
    const float4 v = x[i];
    float* o = out + (size_t)i * NTOK;
    #pragma unroll
    for (int t = 0; t < NTOK; ++t)
        o[t] = v.x * w[t*4] + v.y * w[t*4 + 1] + v.z * w[t*4 + 2] + v.w * w[t*4 + 3] + bbias[t];
}

extern "C" void kernel_launch(void* const* d_in, const int* in_sizes, int n_in,
                              void* d_out, int out_size, void* d_ws, size_t ws_size,
                              hipStream_t stream) {
    const int*   patches = (const int*)d_in[0];
    const int*   mask    = (const int*)d_in[1];
    const float* em      = (const float*)d_in[2];
    const float* rel     = (const float*)d_in[3];
    const float* w1      = (const float*)d_in[4];
    const float* b1      = (const float*)d_in[5];
    const float* w2      = (const float*)d_in[6];
    const float* b2      = (const float*)d_in[7];
    const float* ln1w    = (const float*)d_in[8];
    const float* ln1b    = (const float*)d_in[9];
    const float* ln2w    = (const float*)d_in[10];
    const float* ln2b    = (const float*)d_in[11];
    const float* fcw     = (const float*)d_in[12];
    const float* fcb     = (const float*)d_in[13];
    float* out = (float*)d_out;

    float4* xA = (float4*)d_ws;
    float4* xB = xA + BB * SS;

    embed_kernel<<<BB * SS / 256, 256, 0, stream>>>(patches, mask, em, xA);

    float4* xi = xA;
    float4* xo = xB;
    for (int l = 0; l < 4; ++l) {
        layer_kernel<<<dim3(16, BB), 1024, 0, stream>>>(
            xi, xo, mask,
            rel + l * NREL * 4,
            w1 + l * 64, b1 + l * 16, w2 + l * 64, b2 + l * 4,
            ln1w + l * 4, ln1b + l * 4, ln2w + l * 4, ln2b + l * 4);
        float4* t = xi; xi = xo; xo = t;
    }

    fc_kernel<<<BB * SS / 256, 256, 0, stream>>>(xi, fcw, fcb, out);
}

// Round 3
// 90.243 us; speedup vs baseline: 4.6311x; 1.9607x over previous
//
#include <hip/hip_runtime.h>

#define NTOK 17
#define FFD 16
#define BB 16
#define SS 2048

// The entire reference network collapses to a 17-entry lookup table:
//  - attendable keys (mask==1) all carry the mask-token embedding -> identical
//    value vectors at layer 1; attention out = that shared vector exactly
//    (softmax weights sum to 1), independent of scores/rel-bias.
//  - all other ops are per-position elementwise, so equal states stay equal
//    across layers (masked positions stay mutually identical inductively).
//  => logits(position) = F(state), state = mask ? 16 : patch, 17 states.
// Wave 0 of each block computes the 17x17 table (4 layers, lane=state,
// v* broadcast from lane 16 via shfl); all threads then gather+store.

__global__ __launch_bounds__(256) void vit_kernel(
    const int* __restrict__ patches, const int* __restrict__ mask,
    const float* __restrict__ em,
    const float* __restrict__ w1, const float* __restrict__ b1,
    const float* __restrict__ w2, const float* __restrict__ b2,
    const float* __restrict__ ln1w, const float* __restrict__ ln1b,
    const float* __restrict__ ln2w, const float* __restrict__ ln2b,
    const float* __restrict__ fcw, const float* __restrict__ fcb,
    float4* __restrict__ out)
{
    __shared__ float tbl[NTOK * NTOK + 3];
    const int tid = threadIdx.x;

    if (tid < 64) {
        const int lane = tid;
        const int s = lane < NTOK ? lane : 16;
        const float4 e4 = ((const float4*)em)[s];
        float x0 = e4.x, x1 = e4.y, x2 = e4.z, x3 = e4.w;

        #pragma unroll
        for (int l = 0; l < 4; ++l) {
            const float* W1  = w1  + l * 64;
            const float* B1  = b1  + l * 16;
            const float* W2  = w2  + l * 64;
            const float* B2  = b2  + l * 4;
            const float* L1w = ln1w + l * 4; const float* L1b = ln1b + l * 4;
            const float* L2w = ln2w + l * 4; const float* L2b = ln2b + l * 4;

            // attention output == value of the masked/state-16 token
            const float v0 = __shfl(x0, 16), v1 = __shfl(x1, 16);
            const float v2 = __shfl(x2, 16), v3 = __shfl(x3, 16);
            float h0 = x0 + v0, h1 = x1 + v1, h2 = x2 + v2, h3 = x3 + v3;
            // LN1
            float mu = 0.25f * (h0 + h1 + h2 + h3);
            float d0 = h0 - mu, d1 = h1 - mu, d2 = h2 - mu, d3 = h3 - mu;
            float var = 0.25f * (d0*d0 + d1*d1 + d2*d2 + d3*d3);
            float rs = rsqrtf(var + 1e-5f);
            h0 = d0 * rs * L1w[0] + L1b[0];
            h1 = d1 * rs * L1w[1] + L1b[1];
            h2 = d2 * rs * L1w[2] + L1b[2];
            h3 = d3 * rs * L1w[3] + L1b[3];
            // FF: relu(h @ W1 + B1) @ W2 + B2, residual
            float f0 = B2[0], f1 = B2[1], f2 = B2[2], f3 = B2[3];
            #pragma unroll
            for (int k = 0; k < FFD; ++k) {
                float f = h0 * W1[k] + h1 * W1[16 + k] + h2 * W1[32 + k] + h3 * W1[48 + k] + B1[k];
                f = fmaxf(f, 0.f);
                f0 += f * W2[k*4 + 0]; f1 += f * W2[k*4 + 1];
                f2 += f * W2[k*4 + 2]; f3 += f * W2[k*4 + 3];
            }
            float t0 = h0 + f0, t1 = h1 + f1, t2 = h2 + f2, t3 = h3 + f3;
            // LN2
            mu = 0.25f * (t0 + t1 + t2 + t3);
            d0 = t0 - mu; d1 = t1 - mu; d2 = t2 - mu; d3 = t3 - mu;
            var = 0.25f * (d0*d0 + d1*d1 + d2*d2 + d3*d3);
            rs = rsqrtf(var + 1e-5f);
            x0 = d0 * rs * L2w[0] + L2b[0];
            x1 = d1 * rs * L2w[1] + L2b[1];
            x2 = d2 * rs * L2w[2] + L2b[2];
            x3 = d3 * rs * L2w[3] + L2b[3];
        }

        if (lane < NTOK) {
            #pragma unroll
            for (int t = 0; t < NTOK; ++t) {
                const float4 w = ((const float4*)fcw)[t];
                tbl[lane * NTOK + t] = x0*w.x + x1*w.y + x2*w.z + x3*w.w + fcb[t];
            }
        }
    }
    __syncthreads();

    // gather: out element e = tbl[state(e/17)*17 + e%17], float4 stores
    const int e4i = blockIdx.x * 256 + tid;
    const int e = e4i * 4;
    float r[4];
    #pragma unroll
    for (int k = 0; k < 4; ++k) {
        const unsigned ee = (unsigned)(e + k);
        const unsigned i = ee / 17u;           // magic-mul division
        const unsigned t = ee - i * 17u;
        const int st = mask[i] ? 16 : patches[i];
        r[k] = tbl[st * NTOK + t];
    }
    out[e4i] = make_float4(r[0], r[1], r[2], r[3]);
}

extern "C" void kernel_launch(void* const* d_in, const int* in_sizes, int n_in,
                              void* d_out, int out_size, void* d_ws, size_t ws_size,
                              hipStream_t stream) {
    const int*   patches = (const int*)d_in[0];
    const int*   mask    = (const int*)d_in[1];
    const float* em      = (const float*)d_in[2];
    // d_in[3] = rel_emb: provably unused (attention output is score-independent)
    const float* w1      = (const float*)d_in[4];
    const float* b1      = (const float*)d_in[5];
    const float* w2      = (const float*)d_in[6];
    const float* b2      = (const float*)d_in[7];
    const float* ln1w    = (const float*)d_in[8];
    const float* ln1b    = (const float*)d_in[9];
    const float* ln2w    = (const float*)d_in[10];
    const float* ln2b    = (const float*)d_in[11];
    const float* fcw     = (const float*)d_in[12];
    const float* fcb     = (const float*)d_in[13];
    float4* out = (float4*)d_out;

    // out_size = 16*2048*17 = 557056 floats = 139264 float4 = 544 blocks * 256
    const int nf4 = (BB * SS * NTOK) / 4;
    vit_kernel<<<nf4 / 256, 256, 0, stream>>>(
        patches, mask, em, w1, b1, w2, b2,
        ln1w, ln1b, ln2w, ln2b, fcw, fcb, out);
}

// Round 4
// 89.254 us; speedup vs baseline: 4.6825x; 1.0111x over previous
//
#include <hip/hip_runtime.h>

#define NTOK 17
#define FFD 16
#define BB 16
#define SS 2048

// The entire reference network collapses to a 17-entry lookup table:
//  - attendable keys (mask==1) all carry the mask-token embedding -> identical
//    value vectors at layer 1; attention out = that shared vector exactly
//    (softmax weights sum to 1), independent of scores/rel-bias.
//  - all other ops are per-position elementwise, so equal states stay equal
//    across layers (masked positions stay mutually identical inductively).
//  => logits(position) = F(state), state = mask ? 16 : patch, 17 states.
// Wave 0 of each block computes the 17x17 table (lane=state, v* broadcast
// from lane 16 via shfl); all threads gather+store. Gather's global loads
// and index math are hoisted ABOVE the table chain / __syncthreads so the
// ~200-900cyc load latency hides under the serial table compute.

__global__ __launch_bounds__(256) void vit_kernel(
    const int* __restrict__ patches, const int* __restrict__ mask,
    const float* __restrict__ em,
    const float* __restrict__ w1, const float* __restrict__ b1,
    const float* __restrict__ w2, const float* __restrict__ b2,
    const float* __restrict__ ln1w, const float* __restrict__ ln1b,
    const float* __restrict__ ln2w, const float* __restrict__ ln2b,
    const float* __restrict__ fcw, const float* __restrict__ fcb,
    float4* __restrict__ out)
{
    __shared__ float tbl[NTOK * NTOK + 3];
    const int tid = threadIdx.x;

    // ---- gather prep: issue global loads FIRST (hidden under table chain) ----
    const int e4i = blockIdx.x * 256 + tid;
    const int e = e4i * 4;
    // 4 consecutive elements span at most 2 positions i = e/17
    const unsigned iA = (unsigned)e / 17u;            // magic-mul division
    const unsigned iB = (unsigned)(e + 3) / 17u;
    const int mA = mask[iA],    mB = mask[iB];
    const int pA = patches[iA], pB = patches[iB];
    const unsigned tA = (unsigned)e - iA * 17u;       // t offset of element e
    const int baseA = (mA ? 16 : pA) * NTOK;
    const int baseB = (mB ? 16 : pB) * NTOK;
    int addr[4];
    #pragma unroll
    for (int k = 0; k < 4; ++k) {
        const unsigned t = tA + (unsigned)k;
        addr[k] = (t < 17u) ? (baseA + (int)t) : (baseB + (int)(t - 17u));
    }

    // ---- wave 0: compute the 17x17 table ----
    if (tid < 64) {
        const int lane = tid;
        const int s = lane < NTOK ? lane : 16;
        const float4 e4 = ((const float4*)em)[s];
        float x0 = e4.x, x1 = e4.y, x2 = e4.z, x3 = e4.w;

        #pragma unroll
        for (int l = 0; l < 4; ++l) {
            const float* W1  = w1  + l * 64;
            const float* B1  = b1  + l * 16;
            const float* W2  = w2  + l * 64;
            const float* B2  = b2  + l * 4;
            const float* L1w = ln1w + l * 4; const float* L1b = ln1b + l * 4;
            const float* L2w = ln2w + l * 4; const float* L2b = ln2b + l * 4;

            // attention output == value of the masked/state-16 token
            const float v0 = __shfl(x0, 16), v1 = __shfl(x1, 16);
            const float v2 = __shfl(x2, 16), v3 = __shfl(x3, 16);
            float h0 = x0 + v0, h1 = x1 + v1, h2 = x2 + v2, h3 = x3 + v3;
            // LN1
            float mu = 0.25f * (h0 + h1 + h2 + h3);
            float d0 = h0 - mu, d1 = h1 - mu, d2 = h2 - mu, d3 = h3 - mu;
            float var = 0.25f * (d0*d0 + d1*d1 + d2*d2 + d3*d3);
            float rs = rsqrtf(var + 1e-5f);
            h0 = d0 * rs * L1w[0] + L1b[0];
            h1 = d1 * rs * L1w[1] + L1b[1];
            h2 = d2 * rs * L1w[2] + L1b[2];
            h3 = d3 * rs * L1w[3] + L1b[3];
            // FF: relu(h @ W1 + B1) @ W2 + B2, residual
            float f0 = B2[0], f1 = B2[1], f2 = B2[2], f3 = B2[3];
            #pragma unroll
            for (int k = 0; k < FFD; ++k) {
                float f = h0 * W1[k] + h1 * W1[16 + k] + h2 * W1[32 + k] + h3 * W1[48 + k] + B1[k];
                f = fmaxf(f, 0.f);
                f0 += f * W2[k*4 + 0]; f1 += f * W2[k*4 + 1];
                f2 += f * W2[k*4 + 2]; f3 += f * W2[k*4 + 3];
            }
            float t0 = h0 + f0, t1 = h1 + f1, t2 = h2 + f2, t3 = h3 + f3;
            // LN2
            mu = 0.25f * (t0 + t1 + t2 + t3);
            d0 = t0 - mu; d1 = t1 - mu; d2 = t2 - mu; d3 = t3 - mu;
            var = 0.25f * (d0*d0 + d1*d1 + d2*d2 + d3*d3);
            rs = rsqrtf(var + 1e-5f);
            x0 = d0 * rs * L2w[0] + L2b[0];
            x1 = d1 * rs * L2w[1] + L2b[1];
            x2 = d2 * rs * L2w[2] + L2b[2];
            x3 = d3 * rs * L2w[3] + L2b[3];
        }

        if (lane < NTOK) {
            #pragma unroll
            for (int t = 0; t < NTOK; ++t) {
                const float4 w = ((const float4*)fcw)[t];
                tbl[lane * NTOK + t] = x0*w.x + x1*w.y + x2*w.z + x3*w.w + fcb[t];
            }
        }
    }
    __syncthreads();

    // ---- gather: pure LDS reads + coalesced float4 store ----
    out[e4i] = make_float4(tbl[addr[0]], tbl[addr[1]], tbl[addr[2]], tbl[addr[3]]);
}

extern "C" void kernel_launch(void* const* d_in, const int* in_sizes, int n_in,
                              void* d_out, int out_size, void* d_ws, size_t ws_size,
                              hipStream_t stream) {
    const int*   patches = (const int*)d_in[0];
    const int*   mask    = (const int*)d_in[1];
    const float* em      = (const float*)d_in[2];
    // d_in[3] = rel_emb: provably unused (attention output is score-independent)
    const float* w1      = (const float*)d_in[4];
    const float* b1      = (const float*)d_in[5];
    const float* w2      = (const float*)d_in[6];
    const float* b2      = (const float*)d_in[7];
    const float* ln1w    = (const float*)d_in[8];
    const float* ln1b    = (const float*)d_in[9];
    const float* ln2w    = (const float*)d_in[10];
    const float* ln2b    = (const float*)d_in[11];
    const float* fcw     = (const float*)d_in[12];
    const float* fcb     = (const float*)d_in[13];
    float4* out = (float4*)d_out;

    // out_size = 16*2048*17 = 557056 floats = 139264 float4 = 544 blocks * 256
    const int nf4 = (BB * SS * NTOK) / 4;
    vit_kernel<<<nf4 / 256, 256, 0, stream>>>(
        patches, mask, em, w1, b1, w2, b2,
        ln1w, ln1b, ln2w, ln2b, fcw, fcb, out);
}